// Round 1
// baseline (897.308 us; speedup 1.0000x reference)
//
#include <hip/hip_runtime.h>

// RNN-T loss, fused pipeline:
//   K1: per-(n,t,u) logsumexp over C=512 -> blank/emit log-probs scattered
//       into DIAGONAL-major scratch (makes K2's loads coalesced).
//   K2: one wave per sample, anti-diagonal alpha recursion, shuffle for the
//       u-1 neighbor, 2-deep register prefetch of diagonal rows.
//   K3: mean of per-sample losses -> d_out[0].

#define C_CLASSES 512

__device__ __forceinline__ float wave_max(float v) {
    for (int off = 32; off > 0; off >>= 1)
        v = fmaxf(v, __shfl_xor(v, off, 64));
    return v;
}
__device__ __forceinline__ float wave_sum(float v) {
    for (int off = 32; off > 0; off >>= 1)
        v += __shfl_xor(v, off, 64);
    return v;
}
// sentinel-safe logaddexp: for a=b=-1e30 gives -1e30+ln2 (fine); never NaN.
__device__ __forceinline__ float lae(float a, float b) {
    float m = fmaxf(a, b);
    float t = __expf(-fabsf(a - b));
    return m + __logf(1.0f + t);
}

// ---------------- K1 ----------------
// One wave per row of 512 logits. Lane i loads float4 at [4i] and [256+4i]
// (both fully coalesced 1 KB wave transactions).
// blank value (t,u) is consumed at diag d=t+u+1 slot u;
// emit value (t,uu) is consumed at diag d=t+uu+1 slot uu+1.
__global__ __launch_bounds__(256) void k1_lse(
    const float* __restrict__ act, const int* __restrict__ tgt,
    float* __restrict__ blankD, float* __restrict__ emitD,
    int N, int T, int U, int rowsTotal, int dstride, int sampleStride)
{
    const int wave = threadIdx.x >> 6;
    const int lane = threadIdx.x & 63;
    const int r = blockIdx.x * 4 + wave;
    if (r >= rowsTotal) return;

    const int U1 = U + 1;
    const int TU1 = T * U1;
    const int n = r / TU1;
    const int rem = r - n * TU1;
    const int t = rem / U1;
    const int u = rem - t * U1;

    const float4* rp = (const float4*)(act + (size_t)r * C_CLASSES);
    const float4 a = rp[lane];       // classes 4*lane .. 4*lane+3
    const float4 b = rp[64 + lane];  // classes 256+4*lane ..

    float m = fmaxf(fmaxf(a.x, a.y), fmaxf(a.z, a.w));
    m = fmaxf(m, fmaxf(fmaxf(b.x, b.y), fmaxf(b.z, b.w)));
    m = wave_max(m);
    float s = __expf(a.x - m) + __expf(a.y - m) + __expf(a.z - m) + __expf(a.w - m)
            + __expf(b.x - m) + __expf(b.y - m) + __expf(b.z - m) + __expf(b.w - m);
    s = wave_sum(s);
    const float lse = m + __logf(s);

    const int d = t + u + 1;
    const size_t base = (size_t)n * sampleStride + (size_t)d * dstride;
    if (lane == 0)
        blankD[base + u] = a.x - lse;          // class 0 lives in lane0.a.x
    if (u < U) {
        const int k = tgt[n * U + u];          // 1..C-1
        const int owner = (k < 256) ? (k >> 2) : ((k - 256) >> 2);
        if (lane == owner) {
            const float4 src = (k < 256) ? a : b;
            const int kk = k & 3;
            const float v = (kk & 2) ? ((kk & 1) ? src.w : src.z)
                                     : ((kk & 1) ? src.y : src.x);
            emitD[base + (u + 1)] = v - lse;
        }
    }
}

// ---------------- K2 ----------------
// One 64-lane wave per sample. Lane l owns u=2l and u=2l+1; lane 63 also
// owns u=128 (requires U==128 layout, which this problem has).
// alpha[t,u] = lae(alpha[t-1,u]+blank[t-1,u], alpha[t,u-1]+emit[t,u-1]).
// Both operands of cell (t,u) at diag d live on diag d-1; the u-1 neighbor
// is p1 of lane l-1 (one __shfl_up) or own p0. No barriers.
__global__ __launch_bounds__(64) void k2_alpha(
    const float* __restrict__ blankD, const float* __restrict__ emitD,
    const int* __restrict__ alen, const int* __restrict__ tlen,
    float* __restrict__ losses, int dstride, int sampleStride)
{
    const int n = blockIdx.x;
    const int l = threadIdx.x;
    const int Tn = alen[n];
    const int Un = tlen[n];
    const int Tn1 = Tn - 1;
    const int Dend = Tn1 + Un;

    const float* __restrict__ bS = blankD + (size_t)n * sampleStride;
    const float* __restrict__ eS = emitD  + (size_t)n * sampleStride;

    const float NEG = -1e30f;
    const int u0 = 2 * l, u1 = 2 * l + 1;

    float p0 = (l == 0) ? 0.0f : NEG;   // alpha[0,0] = 0 at diag 0
    float p1 = NEG, p2 = NEG;

    // 2-deep register prefetch of diagonal rows (coalesced float2 + slot128)
    float2 bA, eA, bB, eB;
    float b2A, e2A, b2B, e2B;
#define LDIAG(d, bb, ee, b2, e2)                                   \
    {                                                              \
        const float* brow = bS + (size_t)(d) * dstride;            \
        const float* erow = eS + (size_t)(d) * dstride;            \
        bb = *(const float2*)(brow + u0);                          \
        ee = *(const float2*)(erow + u0);                          \
        b2 = brow[128]; e2 = erow[128];                            \
    }

    LDIAG(1, bA, eA, b2A, e2A);
    LDIAG(2, bB, eB, b2B, e2B);

    for (int d = 1; d <= Dend; ++d) {
        const float2 bb = bA, ee = eA;
        const float b2 = b2A, e2 = e2A;
        bA = bB; eA = eB; b2A = b2B; e2A = e2B;
        int dpf = d + 2; if (dpf > Dend + 1) dpf = Dend + 1;
        LDIAG(dpf, bB, eB, b2B, e2B);

        const float pm1 = __shfl_up(p1, 1, 64);  // alpha at u0-1 (prev diag)

        const int t0 = d - u0, t1 = d - u1, t2 = d - 128;
        const bool v0 = (t0 >= 0) && (t0 <= Tn1) && (u0 <= Un);
        const bool v1 = (t1 >= 0) && (t1 <= Tn1) && (u1 <= Un);
        const bool v2 = (t2 >= 0) && (t2 <= Tn1) && (128 <= Un);

        const float a0 = (v0 && t0 >= 1) ? p0 + bb.x : NEG;
        const float g0 = (v0 && u0 >= 1) ? pm1 + ee.x : NEG;
        const float a1 = (v1 && t1 >= 1) ? p1 + bb.y : NEG;
        const float g1 = v1 ? p0 + ee.y : NEG;   // u1 >= 1 always
        const float a2 = (v2 && t2 >= 1) ? p2 + b2 : NEG;
        const float g2 = v2 ? p1 + e2 : NEG;     // alpha[t2,127] is own p1

        const float n0 = lae(a0, g0);
        const float n1 = lae(a1, g1);
        const float n2 = lae(a2, g2);
        p0 = n0; p1 = n1; p2 = n2;
    }
#undef LDIAG

    // ll = alpha[Tn-1, Un] + blank[Tn-1, Un]; blank stored at diag Dend+1.
    const float fb = bS[(size_t)(Dend + 1) * dstride + Un];
    if (u0 == Un) losses[n] = -(p0 + fb);
    if (u1 == Un) losses[n] = -(p1 + fb);
    if (l == 63 && Un == 128) losses[n] = -(p2 + fb);
}

// ---------------- K3 ----------------
__global__ void k3_mean(const float* __restrict__ losses, float* __restrict__ out, int N)
{
    if (threadIdx.x == 0) {
        float s = 0.0f;
        for (int i = 0; i < N; ++i) s += losses[i];
        out[0] = s / (float)N;
    }
}

extern "C" void kernel_launch(void* const* d_in, const int* in_sizes, int n_in,
                              void* d_out, int out_size, void* d_ws, size_t ws_size,
                              hipStream_t stream)
{
    const float* act  = (const float*)d_in[0];
    const int*   tgt  = (const int*)d_in[1];
    const int*   alen = (const int*)d_in[2];
    const int*   tlen = (const int*)d_in[3];

    const int N  = in_sizes[2];
    const int U  = in_sizes[1] / N;          // 128
    const int U1 = U + 1;                    // 129
    const int T  = (int)((long long)in_sizes[0] / ((long long)N * U1 * C_CLASSES)); // 256

    const int rows = N * T * U1;             // 264192
    const int dstride = U1 + 1;              // 130 (even -> float2-aligned rows)
    const int sampleStride = (T + U + 1) * dstride;  // 385*130 = 50050

    float* ws = (float*)d_ws;
    float* blankD = ws;
    float* emitD  = ws + (size_t)N * sampleStride;
    float* losses = emitD + (size_t)N * sampleStride;
    // ws usage: (2*N*sampleStride + N) * 4 B ~= 3.2 MB

    k1_lse<<<(rows + 3) / 4, 256, 0, stream>>>(act, tgt, blankD, emitD,
                                               N, T, U, rows, dstride, sampleStride);
    k2_alpha<<<N, 64, 0, stream>>>(blankD, emitD, alen, tlen, losses,
                                   dstride, sampleStride);
    k3_mean<<<1, 64, 0, stream>>>(losses, (float*)d_out, N);
}

// Round 2
// 840.018 us; speedup vs baseline: 1.0682x; 1.0682x over previous
//
#include <hip/hip_runtime.h>

// RNN-T loss, fused pipeline:
//   K1: per-(n,t,u) logsumexp over C=512 -> blank/emit log-probs scattered
//       into DIAGONAL-major scratch (makes K2's loads coalesced).
//       act loads are NON-TEMPORAL so the 541 MB stream doesn't evict the
//       3.2 MB scratch from L2 (K2 wants it cached).
//   K2: one wave per sample, anti-diagonal alpha recursion, shuffle for the
//       u-1 neighbor, 8-deep register prefetch of diagonal rows (covers
//       ~600+ cyc of L2/L3 latency; only 8 waves run on the whole GPU).
//       Mean-reduction folded in via device-scope atomics (no K3).

#define C_CLASSES 512

typedef float v4f __attribute__((ext_vector_type(4)));

__device__ __forceinline__ float wave_max(float v) {
    for (int off = 32; off > 0; off >>= 1)
        v = fmaxf(v, __shfl_xor(v, off, 64));
    return v;
}
__device__ __forceinline__ float wave_sum(float v) {
    for (int off = 32; off > 0; off >>= 1)
        v += __shfl_xor(v, off, 64);
    return v;
}
// sentinel-safe logaddexp: for a=b=-1e30 gives -1e30+ln2 (fine); never NaN.
__device__ __forceinline__ float lae(float a, float b) {
    float m = fmaxf(a, b);
    float t = __expf(-fabsf(a - b));
    return m + __logf(1.0f + t);
}

// ---------------- K1 ----------------
// One wave per row of 512 logits. Lane i loads float4 at [4i] and [256+4i]
// (both fully coalesced 1 KB wave transactions, non-temporal).
// blank value (t,u) is consumed at diag d=t+u+1 slot u;
// emit value (t,uu) is consumed at diag d=t+uu+1 slot uu+1.
__global__ __launch_bounds__(256) void k1_lse(
    const float* __restrict__ act, const int* __restrict__ tgt,
    float* __restrict__ blankD, float* __restrict__ emitD,
    float* __restrict__ accum, int* __restrict__ count,
    int N, int T, int U, int rowsTotal, int dstride, int sampleStride)
{
    // zero the cross-kernel reduction slots (ws is re-poisoned every call)
    if (blockIdx.x == 0 && threadIdx.x == 0) { accum[0] = 0.0f; count[0] = 0; }

    const int wave = threadIdx.x >> 6;
    const int lane = threadIdx.x & 63;
    const int r = blockIdx.x * 4 + wave;
    if (r >= rowsTotal) return;

    const int U1 = U + 1;
    const int TU1 = T * U1;
    const int n = r / TU1;
    const int rem = r - n * TU1;
    const int t = rem / U1;
    const int u = rem - t * U1;

    const v4f* rp = (const v4f*)(act + (size_t)r * C_CLASSES);
    const v4f a = __builtin_nontemporal_load(rp + lane);       // classes 4*lane..
    const v4f b = __builtin_nontemporal_load(rp + 64 + lane);  // classes 256+4*lane..

    float m = fmaxf(fmaxf(a.x, a.y), fmaxf(a.z, a.w));
    m = fmaxf(m, fmaxf(fmaxf(b.x, b.y), fmaxf(b.z, b.w)));
    m = wave_max(m);
    float s = __expf(a.x - m) + __expf(a.y - m) + __expf(a.z - m) + __expf(a.w - m)
            + __expf(b.x - m) + __expf(b.y - m) + __expf(b.z - m) + __expf(b.w - m);
    s = wave_sum(s);
    const float lse = m + __logf(s);

    const int d = t + u + 1;
    const size_t base = (size_t)n * sampleStride + (size_t)d * dstride;
    if (lane == 0)
        blankD[base + u] = a.x - lse;          // class 0 lives in lane0.a.x
    if (u < U) {
        const int k = tgt[n * U + u];          // 1..C-1
        const int owner = (k < 256) ? (k >> 2) : ((k - 256) >> 2);
        if (lane == owner) {
            const v4f src = (k < 256) ? a : b;
            const int kk = k & 3;
            const float v = (kk & 2) ? ((kk & 1) ? src.w : src.z)
                                     : ((kk & 1) ? src.y : src.x);
            emitD[base + (u + 1)] = v - lse;
        }
    }
}

// ---------------- K2 ----------------
// One 64-lane wave per sample. Lane l owns u=2l and u=2l+1; lane 63 also
// owns u=128 (requires U==128 layout, which this problem has).
// alpha[t,u] = lae(alpha[t-1,u]+blank[t-1,u], alpha[t,u-1]+emit[t,u-1]).
// Both operands of cell (t,u) at diag d live on diag d-1; the u-1 neighbor
// is p1 of lane l-1 (one __shfl_up) or own p0. No barriers.
// 8-deep register prefetch: stage j holds diagonal d0+j; consumed stages are
// immediately refilled with diagonal d+8 (clamped), covering miss latency.
#define PF 8
__global__ __launch_bounds__(64) void k2_alpha(
    const float* __restrict__ blankD, const float* __restrict__ emitD,
    const int* __restrict__ alen, const int* __restrict__ tlen,
    float* __restrict__ accum, int* __restrict__ count,
    float* __restrict__ out, int N, int dstride, int sampleStride)
{
    const int n = blockIdx.x;
    const int l = threadIdx.x;
    const int Tn = alen[n];
    const int Un = tlen[n];
    const int Tn1 = Tn - 1;
    const int Dend = Tn1 + Un;

    const float* __restrict__ bS = blankD + (size_t)n * sampleStride;
    const float* __restrict__ eS = emitD  + (size_t)n * sampleStride;

    const float NEG = -1e30f;
    const int u0 = 2 * l, u1 = 2 * l + 1;

    float p0 = (l == 0) ? 0.0f : NEG;   // alpha[0,0] = 0 at diag 0
    float p1 = NEG, p2 = NEG;

    float2 bQ[PF], eQ[PF];
    float b2Q[PF], e2Q[PF];
#define LDIAG(d, bb, ee, b2, e2)                                   \
    {                                                              \
        const float* brow = bS + (size_t)(d) * dstride;            \
        const float* erow = eS + (size_t)(d) * dstride;            \
        bb = *(const float2*)(brow + u0);                          \
        ee = *(const float2*)(erow + u0);                          \
        b2 = brow[128]; e2 = erow[128];                            \
    }

#pragma unroll
    for (int j = 0; j < PF; ++j) {
        int dl = 1 + j; if (dl > Dend + 1) dl = Dend + 1;
        LDIAG(dl, bQ[j], eQ[j], b2Q[j], e2Q[j]);
    }

    for (int d0 = 1; d0 <= Dend; d0 += PF) {
#pragma unroll
        for (int j = 0; j < PF; ++j) {
            const int d = d0 + j;
            if (d > Dend) break;

            const float2 bb = bQ[j], ee = eQ[j];
            const float b2 = b2Q[j], e2 = e2Q[j];
            int dpf = d + PF; if (dpf > Dend + 1) dpf = Dend + 1;
            LDIAG(dpf, bQ[j], eQ[j], b2Q[j], e2Q[j]);

            const float pm1 = __shfl_up(p1, 1, 64);  // alpha at u0-1 (prev diag)

            const int t0 = d - u0, t1 = d - u1, t2 = d - 128;
            const bool v0 = (t0 >= 0) && (t0 <= Tn1) && (u0 <= Un);
            const bool v1 = (t1 >= 0) && (t1 <= Tn1) && (u1 <= Un);
            const bool v2 = (t2 >= 0) && (t2 <= Tn1) && (128 <= Un);

            const float a0 = (v0 && t0 >= 1) ? p0 + bb.x : NEG;
            const float g0 = (v0 && u0 >= 1) ? pm1 + ee.x : NEG;
            const float a1 = (v1 && t1 >= 1) ? p1 + bb.y : NEG;
            const float g1 = v1 ? p0 + ee.y : NEG;   // u1 >= 1 always
            const float a2 = (v2 && t2 >= 1) ? p2 + b2 : NEG;
            const float g2 = v2 ? p1 + e2 : NEG;     // alpha[t2,127] is own p1

            p0 = lae(a0, g0);
            p1 = lae(a1, g1);
            p2 = lae(a2, g2);
        }
    }
#undef LDIAG

    // ll = alpha[Tn-1, Un] + blank[Tn-1, Un]; blank stored at diag Dend+1.
    const float fb = bS[(size_t)(Dend + 1) * dstride + Un];
    float lv = 0.0f; bool own = false;
    if (u0 == Un)               { lv = -(p0 + fb); own = true; }
    if (u1 == Un)               { lv = -(p1 + fb); own = true; }
    if (l == 63 && Un == 128)   { lv = -(p2 + fb); own = true; }

    if (own) {  // exactly one lane per block
        atomicAdd(accum, lv);
        __threadfence();
        const int old = atomicAdd(count, 1);
        if (old == N - 1) {
            __threadfence();
            const float s = atomicAdd(accum, 0.0f);  // coherent read
            out[0] = s / (float)N;
        }
    }
}
#undef PF

extern "C" void kernel_launch(void* const* d_in, const int* in_sizes, int n_in,
                              void* d_out, int out_size, void* d_ws, size_t ws_size,
                              hipStream_t stream)
{
    const float* act  = (const float*)d_in[0];
    const int*   tgt  = (const int*)d_in[1];
    const int*   alen = (const int*)d_in[2];
    const int*   tlen = (const int*)d_in[3];

    const int N  = in_sizes[2];
    const int U  = in_sizes[1] / N;          // 128
    const int U1 = U + 1;                    // 129
    const int T  = (int)((long long)in_sizes[0] / ((long long)N * U1 * C_CLASSES)); // 256

    const int rows = N * T * U1;             // 264192
    const int dstride = U1 + 1;              // 130 (even -> float2-aligned rows)
    const int sampleStride = (T + U + 1) * dstride;  // 385*130 = 50050

    float* ws = (float*)d_ws;
    float* accum  = ws;                      // [0]: loss accumulator
    int*   count  = (int*)(ws + 1);          // [1]: finished-block counter
    float* blankD = ws + 2;                  // even offset -> float2 aligned
    float* emitD  = blankD + (size_t)N * sampleStride;
    // ws usage: (2 + 2*N*sampleStride) * 4 B ~= 3.2 MB

    k1_lse<<<(rows + 3) / 4, 256, 0, stream>>>(act, tgt, blankD, emitD,
                                               accum, count,
                                               N, T, U, rows, dstride, sampleStride);
    k2_alpha<<<N, 64, 0, stream>>>(blankD, emitD, alen, tlen,
                                   accum, count, (float*)d_out,
                                   N, dstride, sampleStride);
}